// Round 6
// baseline (2201.647 us; speedup 1.0000x reference)
//
#include <hip/hip_runtime.h>
#include <stdint.h>

// ISTA_Net fused MFMA implementation for gfx950.  Round 6:
// - Single-pass Phase B/C: z gets a dedicated 64KB LDS buffer [32][1024]
//   (no c-chunks) -> xm not live during Phase B (peak acc 64, was 96),
//   barriers 6->3 per iteration.  LDS total 152KB, 1 block/CU, 8 waves,
//   waves_per_eu(2,2) -> 256 unified regs/wave.
// - Explicit prefetch rings in every phase kc-loop (depth 2-8) to keep
//   ~4 outstanding 1KB A-fragment loads per wave -> cover ~300-600cyc
//   L2/LLC latency (R5 was latency-bound: MfmaUtil 11.5%, 2 waves/SIMD).
// - All prep work merged into ONE kernel (saves launch gaps).
// Shapes: M=1024, N=128, K=256, T=10, BATCH=8192. LAMBD=1.
// Outputs: x_T(2,8192,256) ++ loss_sparse ++ loss_eq/T ++ out_sparse

typedef short s8v __attribute__((ext_vector_type(8)));   // 8 bf16 (4 VGPRs) MFMA operand
typedef short s4v __attribute__((ext_vector_type(4)));
typedef float f16v __attribute__((ext_vector_type(16))); // 32x32 MFMA accumulator

#define MFMA(a, b, c) __builtin_amdgcn_mfma_f32_32x32x16_bf16((a), (b), (c), 0, 0, 0)

__device__ __forceinline__ short f2bf(float f) {
  uint32_t u = __builtin_bit_cast(uint32_t, f);
  u = (u + 0x7FFFu + ((u >> 16) & 1u)) >> 16;   // RNE
  return (short)u;
}
__device__ __forceinline__ float bf2f(short s) {
  uint32_t u = ((uint32_t)(uint16_t)s) << 16;
  return __builtin_bit_cast(float, u);
}

// ---------------- merged prep kernel ----------------
// Packed layout per section: idx = ((tile*KC + kc)*2 + h)*256 + l31*8 + j
//   A-fragment element (l31, h, j) = Src[tile*32 + l31][kc*16 + h*8 + j]
// Block ranges: [0,768) Cbp | [768,1024) WXbp | [1024,3072) E0bp |
//               [3072,5120) E0Tbp | 5120 zero-tail

__global__ void prep_all(const float* __restrict__ W, const float* __restrict__ WX,
                         const float* __restrict__ E0,
                         short* __restrict__ Cbp, short* __restrict__ WXbp,
                         short* __restrict__ E0bp, short* __restrict__ E0Tbp,
                         float* __restrict__ out) {
  const int b = blockIdx.x;
  if (b < 768) {
    // Cbp: sections [C0, C1, -C1] (65536 shorts each), C = WX*W (256x256), KC=16
    const int idx = b * 256 + threadIdx.x;
    const int sec = idx >> 16, r = idx & 65535;
    const int j = r & 7, l31 = (r >> 3) & 31, h = (r >> 8) & 1, kc = (r >> 9) & 15, rt = r >> 13;
    const int i = rt * 32 + l31, col = kc * 16 + h * 8 + j;
    float c0 = 0.f, c1 = 0.f;
    for (int n = 0; n < 128; n++) {
      const float wx0 = WX[i * 128 + n], wx1 = WX[32768 + i * 128 + n];
      const float w0 = W[n * 256 + col], w1 = W[32768 + n * 256 + col];
      c0 += wx0 * w0 - wx1 * w1;
      c1 += wx0 * w1 + wx1 * w0;
    }
    Cbp[idx] = f2bf(sec == 0 ? c0 : (sec == 1 ? c1 : -c1));
  } else if (b < 1024) {
    // WXbp: sections [-WX0, -WX1] (32768 shorts each), rows k(256), cols n(128), KC=8
    const int idx = (b - 768) * 256 + threadIdx.x;
    const int sec = idx >> 15, r = idx & 32767;
    const int j = r & 7, l31 = (r >> 3) & 31, h = (r >> 8) & 1, kc = (r >> 9) & 7, rt = r >> 12;
    const int row = rt * 32 + l31, col = kc * 16 + h * 8 + j;
    WXbp[idx] = f2bf(-WX[sec * 32768 + row * 128 + col]);
  } else if (b < 3072) {
    // E0bp: sections [E0_re, -E0_im] (262144 shorts each), rows m(1024), cols k(256), KC=16
    const int idx = (b - 1024) * 256 + threadIdx.x;
    const int sec = idx >> 18, r = idx & 262143;
    const int j = r & 7, l31 = (r >> 3) & 31, h = (r >> 8) & 1, kc = (r >> 9) & 15, mt = r >> 13;
    const int m = mt * 32 + l31, k = kc * 16 + h * 8 + j;
    const float v = E0[sec * 262144 + m * 256 + k];
    E0bp[idx] = f2bf(sec ? -v : v);
  } else if (b < 5120) {
    // E0Tbp: sections [E0_re^T, -E0_im^T] (262144 shorts each), rows k(256), cols m(1024), KC=64
    const int idx = (b - 3072) * 256 + threadIdx.x;
    const int ch = idx >> 18, r = idx & 262143;
    const int j = r & 7, l31 = (r >> 3) & 31, h = (r >> 8) & 1, kc = (r >> 9) & 63, rt = r >> 15;
    const int krow = rt * 32 + l31, mcol = kc * 16 + h * 8 + j;
    const float v = E0[ch * 262144 + mcol * 256 + krow];
    E0Tbp[idx] = f2bf(ch ? -v : v);
  } else {
    if (threadIdx.x < 3) out[4194304 + threadIdx.x] = 0.f;
  }
}

// ---------------- main fused kernel ----------------
// grid 256 (batch tile of 32), block 512 (8 waves; wave w = row-tile).
// LDS: bufx (32KB) = x  bf16 [2][32][256]
//      bufg (32KB) = gx bf16 [2][32][256]
//      bufz (64KB) = z  bf16 [32][1024]      (single-pass, no chunks)
//      bufy (24KB) = y  bf16 [y0|y1|-y1][32][128]  (persistent)
// Total 152KB -> 1 block/CU.  Rows XOR-swizzled at 16B granules by (row&7).
// Barriers: 3 per iteration (after gx-write, after z-write, after x-write).

__global__ __attribute__((amdgpu_flat_work_group_size(512, 512), amdgpu_waves_per_eu(2, 2)))
void ista_main(
    const float* __restrict__ y,
    const float* __restrict__ etas,
    const float* __restrict__ gammas,
    const short* __restrict__ Cbp,
    const short* __restrict__ WXbp,
    const short* __restrict__ E0bp,
    const short* __restrict__ E0Tbp,
    float* __restrict__ out) {
  __shared__ short bufx[16384];
  __shared__ short bufg[16384];
  __shared__ short bufz[32768];
  __shared__ short bufy[12288];

  const int tid = threadIdx.x;
  const int w = tid >> 6;          // wave 0..7 == row-tile
  const int lane = tid & 63;
  const int l31 = lane & 31;
  const int h = lane >> 5;         // half-wave
  const int sw = l31 & 7;          // swizzle key
  const int b0 = blockIdx.x * 32;
  const int lq = l31 * 8;          // packed-fragment lane offset (shorts)

  // ---- stage y -> bufy: [0]=y_re, [1]=y_im, [2]=-y_im
  {
    const int bt = tid >> 4, j = tid & 15;      // 16 threads per batch row
    const float* yb = y + (size_t)(b0 + bt) * 256;
    const int bsw = (bt & 7);
    #pragma unroll
    for (int rep = 0; rep < 2; rep++) {
      const int jj = j + rep * 16;
      const int ch = jj >> 4, n8 = (jj & 15) << 3;
      const float4 v0 = *(const float4*)(yb + ch * 128 + n8);
      const float4 v1 = *(const float4*)(yb + ch * 128 + n8 + 4);
      s8v pk;
      pk[0] = f2bf(v0.x); pk[1] = f2bf(v0.y); pk[2] = f2bf(v0.z); pk[3] = f2bf(v0.w);
      pk[4] = f2bf(v1.x); pk[5] = f2bf(v1.y); pk[6] = f2bf(v1.z); pk[7] = f2bf(v1.w);
      const int off = bt * 128 + (((n8 >> 3) ^ bsw) << 3);
      *(s8v*)(bufy + ch * 4096 + off) = pk;
      if (ch == 1) {
        s8v nk;
        #pragma unroll
        for (int e = 0; e < 8; e++) nk[e] = pk[e] ^ (short)0x8000;
        *(s8v*)(bufy + 8192 + off) = nk;
      }
    }
  }
  // ---- zero bufx (x = 0): 512 threads x 32 shorts
  {
    s8v z = {0, 0, 0, 0, 0, 0, 0, 0};
    #pragma unroll
    for (int r = 0; r < 4; r++) *(s8v*)(bufx + tid * 32 + r * 8) = z;
  }
  __syncthreads();

  float ls = 0.f, leq = 0.f, cntf = 0.f;
  f16v xm0, xm1;
  #pragma unroll
  for (int r = 0; r < 16; r++) { xm0[r] = 0.f; xm1[r] = 0.f; }

  #pragma unroll 1
  for (int it = 1; it <= 10; it++) {
    const float gam = gammas[it];
    const float eta = etas[it];

    // ======== Phase A: ac = C*x - d~ ; gx = x - gam*ac (both channels) ========
    f16v ac0, ac1;
    #pragma unroll
    for (int r = 0; r < 16; r++) { ac0[r] = 0.f; ac1[r] = 0.f; }
    {
      // -d~ = (-WX) * y ; depth-2 ring
      s8v pw[2][2];
      {
        const int pa = ((w * 8 + 0) * 2 + h) * 256 + lq;
        pw[0][0] = *(const s8v*)(WXbp + pa);
        pw[0][1] = *(const s8v*)(WXbp + 32768 + pa);
      }
      #pragma unroll
      for (int kc = 0; kc < 8; kc++) {
        const int cur = kc & 1, nxt = cur ^ 1;
        if (kc + 1 < 8) {
          const int pa = ((w * 8 + kc + 1) * 2 + h) * 256 + lq;
          pw[nxt][0] = *(const s8v*)(WXbp + pa);
          pw[nxt][1] = *(const s8v*)(WXbp + 32768 + pa);
        }
        const int yo = l31 * 128 + ((((kc * 2 + h)) ^ sw) << 3);
        const s8v by0 = *(const s8v*)(bufy + yo);           // y0
        const s8v by1 = *(const s8v*)(bufy + 4096 + yo);    // y1
        const s8v by1n = *(const s8v*)(bufy + 8192 + yo);   // -y1
        ac0 = MFMA(pw[cur][0], by0, ac0);
        ac0 = MFMA(pw[cur][1], by1n, ac0);
        ac1 = MFMA(pw[cur][0], by1, ac1);
        ac1 = MFMA(pw[cur][1], by0, ac1);
      }
    }
    {
      // + C * x ; depth-4 ring of 3 sections
      s8v pc[4][3];
      #pragma unroll
      for (int p = 0; p < 4; p++) {
        const int pa = ((w * 16 + p) * 2 + h) * 256 + lq;
        pc[p][0] = *(const s8v*)(Cbp + pa);
        pc[p][1] = *(const s8v*)(Cbp + 65536 + pa);
        pc[p][2] = *(const s8v*)(Cbp + 131072 + pa);
      }
      #pragma unroll
      for (int kc = 0; kc < 16; kc++) {
        const int cur = kc & 3;
        const s8v a0 = pc[cur][0], a1 = pc[cur][1], a1n = pc[cur][2];
        if (kc + 4 < 16) {
          const int pa = ((w * 16 + kc + 4) * 2 + h) * 256 + lq;
          pc[cur][0] = *(const s8v*)(Cbp + pa);
          pc[cur][1] = *(const s8v*)(Cbp + 65536 + pa);
          pc[cur][2] = *(const s8v*)(Cbp + 131072 + pa);
        }
        const int xo = l31 * 256 + ((((kc * 2 + h)) ^ sw) << 3);
        const s8v bx0 = *(const s8v*)(bufx + xo);
        const s8v bx1 = *(const s8v*)(bufx + 8192 + xo);
        ac0 = MFMA(a0, bx0, ac0);
        ac0 = MFMA(a1n, bx1, ac0);
        ac1 = MFMA(a0, bx1, ac1);
        ac1 = MFMA(a1, bx0, ac1);
      }
    }
    // gx = x - gam*ac  (x per-lane from LDS bf16); write gx bf16 -> bufg
    #pragma unroll
    for (int r1 = 0; r1 < 4; r1++) {
      const int k0 = w * 32 + 8 * r1 + 4 * h;
      const int idx = l31 * 256 + (((k0 >> 3) ^ sw) << 3) + (k0 & 7);
      const s4v xv0 = *(const s4v*)(bufx + idx);
      const s4v xv1 = *(const s4v*)(bufx + 8192 + idx);
      s4v p0, p1;
      #pragma unroll
      for (int r0 = 0; r0 < 4; r0++) {
        p0[r0] = f2bf(bf2f(xv0[r0]) - gam * ac0[r1 * 4 + r0]);
        p1[r0] = f2bf(bf2f(xv1[r0]) - gam * ac1[r1 * 4 + r0]);
      }
      *(s4v*)(bufg + idx) = p0;
      *(s4v*)(bufg + 8192 + idx) = p1;
    }
    __syncthreads();

    // ======== Phase B: z = Re(E0 * gx), all 1024 m; 4 m-tiles per wave ========
    {
      f16v zz[4];
      #pragma unroll
      for (int q = 0; q < 4; q++)
        #pragma unroll
        for (int r = 0; r < 16; r++) zz[q][r] = 0.f;
      s8v pb[2][4][2];   // depth-2 ring x 4 tiles x 2 sections
      #pragma unroll
      for (int q = 0; q < 4; q++) {
        const int mt = q * 8 + w;
        const int pa = ((mt * 16 + 0) * 2 + h) * 256 + lq;
        pb[0][q][0] = *(const s8v*)(E0bp + pa);
        pb[0][q][1] = *(const s8v*)(E0bp + 262144 + pa);
      }
      #pragma unroll
      for (int kc = 0; kc < 16; kc++) {
        const int cur = kc & 1, nxt = cur ^ 1;
        if (kc + 1 < 16) {
          #pragma unroll
          for (int q = 0; q < 4; q++) {
            const int mt = q * 8 + w;
            const int pa = ((mt * 16 + kc + 1) * 2 + h) * 256 + lq;
            pb[nxt][q][0] = *(const s8v*)(E0bp + pa);
            pb[nxt][q][1] = *(const s8v*)(E0bp + 262144 + pa);
          }
        }
        const int xo = l31 * 256 + ((((kc * 2 + h)) ^ sw) << 3);
        const s8v bg0 = *(const s8v*)(bufg + xo);
        const s8v bg1 = *(const s8v*)(bufg + 8192 + xo);
        #pragma unroll
        for (int q = 0; q < 4; q++) {
          zz[q] = MFMA(pb[cur][q][0], bg0, zz[q]);
          zz[q] = MFMA(pb[cur][q][1], bg1, zz[q]);
        }
      }
      // shrink + losses + store z -> bufz [32][1024]
      #pragma unroll
      for (int q = 0; q < 4; q++) {
        const int mtl = q * 8 + w;
        #pragma unroll
        for (int r1 = 0; r1 < 4; r1++) {
          s4v ps;
          #pragma unroll
          for (int r0 = 0; r0 < 4; r0++) {
            const float v = zz[q][r1 * 4 + r0];
            const float av = fabsf(v) - eta;
            float s = 0.f;
            if (av > 0.f) {
              s = (v > 0.f) ? av : -av;
              ls += av;
              if (it == 10 && av > 1e-3f) cntf += 1.f;
            }
            ps[r0] = f2bf(s);
          }
          const int ml = mtl * 32 + 8 * r1 + 4 * h;
          *(s4v*)(bufz + l31 * 1024 + (((ml >> 3) ^ sw) << 3) + (ml & 7)) = ps;
        }
      }
    }
    __syncthreads();

    // ======== Phase C: xm = [E0_re^T; -E0_im^T] * s, reduce over 1024 m ========
    #pragma unroll
    for (int r = 0; r < 16; r++) { xm0[r] = 0.f; xm1[r] = 0.f; }
    {
      s8v pcr[8][2];   // depth-8 ring
      #pragma unroll
      for (int p = 0; p < 8; p++) {
        const int pa = ((w * 64 + p) * 2 + h) * 256 + lq;
        pcr[p][0] = *(const s8v*)(E0Tbp + pa);
        pcr[p][1] = *(const s8v*)(E0Tbp + 262144 + pa);
      }
      #pragma unroll
      for (int kc = 0; kc < 64; kc++) {
        const int cur = kc & 7;
        const s8v a0 = pcr[cur][0], a1 = pcr[cur][1];
        if (kc + 8 < 64) {
          const int pa = ((w * 64 + kc + 8) * 2 + h) * 256 + lq;
          pcr[cur][0] = *(const s8v*)(E0Tbp + pa);
          pcr[cur][1] = *(const s8v*)(E0Tbp + 262144 + pa);
        }
        const int zo = l31 * 1024 + ((((kc * 2 + h)) ^ sw) << 3);
        const s8v bz = *(const s8v*)(bufz + zo);
        xm0 = MFMA(a0, bz, xm0);
        xm1 = MFMA(a1, bz, xm1);
      }
    }

    // ======== Phase D: huber(gx, xm); x = xm (bf16) -> bufx ========
    #pragma unroll
    for (int r1 = 0; r1 < 4; r1++) {
      const int k0 = w * 32 + 8 * r1 + 4 * h;
      const int idx = l31 * 256 + (((k0 >> 3) ^ sw) << 3) + (k0 & 7);
      const s4v gv0 = *(const s4v*)(bufg + idx);
      const s4v gv1 = *(const s4v*)(bufg + 8192 + idx);
      s4v p0, p1;
      #pragma unroll
      for (int r0 = 0; r0 < 4; r0++) {
        const float x0 = xm0[r1 * 4 + r0], x1 = xm1[r1 * 4 + r0];
        const float d0 = bf2f(gv0[r0]) - x0;
        const float d1 = bf2f(gv1[r0]) - x1;
        const float a0 = fabsf(d0), a1 = fabsf(d1);
        leq += (a0 < 1.f) ? 0.5f * d0 * d0 : (a0 - 0.5f);
        leq += (a1 < 1.f) ? 0.5f * d1 * d1 : (a1 - 0.5f);
        p0[r0] = f2bf(x0);
        p1[r0] = f2bf(x1);
      }
      *(s4v*)(bufx + idx) = p0;
      *(s4v*)(bufx + 8192 + idx) = p1;
    }
    __syncthreads();
  }

  // ---- write x_T (2, 8192, 256) fp32 from final xm (both channels)
  {
    const size_t ob = (size_t)(b0 + l31) * 256;
    #pragma unroll
    for (int r1 = 0; r1 < 4; r1++) {
      const int k0 = w * 32 + 8 * r1 + 4 * h;
      float4 v0, v1;
      v0.x = xm0[r1 * 4 + 0]; v0.y = xm0[r1 * 4 + 1]; v0.z = xm0[r1 * 4 + 2]; v0.w = xm0[r1 * 4 + 3];
      v1.x = xm1[r1 * 4 + 0]; v1.y = xm1[r1 * 4 + 1]; v1.z = xm1[r1 * 4 + 2]; v1.w = xm1[r1 * 4 + 3];
      *(float4*)(out + ob + k0) = v0;
      *(float4*)(out + 2097152 + ob + k0) = v1;
    }
  }
  // ---- scalar reductions
  #pragma unroll
  for (int off = 32; off > 0; off >>= 1) {
    ls += __shfl_down(ls, off);
    leq += __shfl_down(leq, off);
    cntf += __shfl_down(cntf, off);
  }
  if (lane == 0) {
    atomicAdd(out + 4194304, ls * (1.f / 8192.f));
    atomicAdd(out + 4194305, leq * (1.f / (2.f * 256.f * 8192.f * 10.f)));
    atomicAdd(out + 4194306, cntf * (1.f / 8192.f));
  }
}

extern "C" void kernel_launch(void* const* d_in, const int* in_sizes, int n_in,
                              void* d_out, int out_size, void* d_ws, size_t ws_size,
                              hipStream_t stream) {
  (void)in_sizes; (void)n_in; (void)out_size; (void)ws_size;
  const float* y = (const float*)d_in[0];
  const float* W = (const float*)d_in[1];
  const float* WX = (const float*)d_in[2];
  const float* E0 = (const float*)d_in[3];
  const float* etas = (const float*)d_in[4];
  const float* gammas = (const float*)d_in[5];
  float* out = (float*)d_out;

  short* Cbp = (short*)d_ws;           // 3 * 65536
  short* WXbp = Cbp + 196608;          // 2 * 32768
  short* E0bp = WXbp + 65536;          // 2 * 262144
  short* E0Tbp = E0bp + 524288;        // 2 * 262144  (total ~2.6 MB)

  prep_all<<<5121, 256, 0, stream>>>(W, WX, E0, Cbp, WXbp, E0bp, E0Tbp, out);
  ista_main<<<256, 512, 0, stream>>>(y, etas, gammas, Cbp, WXbp, E0bp, E0Tbp, out);
}

// Round 8
// 617.256 us; speedup vs baseline: 3.5668x; 3.5668x over previous
//
#include <hip/hip_runtime.h>
#include <stdint.h>

// ISTA_Net fused MFMA implementation for gfx950.  Round 8:
// R5 structure (passed, 842us: 8 waves, 256 regs/wave, packed weights) +
// FIXED async LDS staging rings for the E0/E0T streams (R7's ring issued
// into slot (kc+4)%4 == kc%4 BEFORE consuming kc -> WAR race -> garbage).
// Correct discipline per step: s_waitcnt vmcnt(N) -> ds_read+MFMA consume
// -> DMA-issue into the just-freed slot.  Prologue = 4 slots (8 loads);
// N = 2*min(3, LAST-kc) handles the tail drain exactly.
// Ring slots are 4 separate __shared__ arrays (wave-private slices), LDS
// pointer passed wave-uniform (HW scatters lane i -> base + 16*i).
// Shapes: M=1024, N=128, K=256, T=10, BATCH=8192. LAMBD=1.
// Outputs: x_T(2,8192,256) ++ loss_sparse ++ loss_eq/T ++ out_sparse

typedef short s8v __attribute__((ext_vector_type(8)));   // 8 bf16 (4 VGPRs) MFMA operand
typedef short s4v __attribute__((ext_vector_type(4)));
typedef float f16v __attribute__((ext_vector_type(16))); // 32x32 MFMA accumulator

#define MFMA(a, b, c) __builtin_amdgcn_mfma_f32_32x32x16_bf16((a), (b), (c), 0, 0, 0)

__device__ __forceinline__ short f2bf(float f) {
  uint32_t u = __builtin_bit_cast(uint32_t, f);
  u = (u + 0x7FFFu + ((u >> 16) & 1u)) >> 16;   // RNE
  return (short)u;
}
__device__ __forceinline__ float bf2f(short s) {
  uint32_t u = ((uint32_t)(uint16_t)s) << 16;
  return __builtin_bit_cast(float, u);
}

// async 16B/lane global->LDS DMA.  g: per-lane global addr (base + lane*16B);
// l: WAVE-UNIFORM LDS base (HW writes lane i's 16B to l + i*16).
__device__ __forceinline__ void glds16(const short* g, short* l) {
  __builtin_amdgcn_global_load_lds(
      (const __attribute__((address_space(1))) void*)g,
      (__attribute__((address_space(3))) void*)l, 16, 0, 0);
}

// compile-time-constant vmcnt wait (folds to one s_waitcnt under #pragma unroll)
__device__ __forceinline__ void waitvm(int n) {
  if (n <= 0)      asm volatile("s_waitcnt vmcnt(0)" ::: "memory");
  else if (n == 2) asm volatile("s_waitcnt vmcnt(2)" ::: "memory");
  else if (n == 4) asm volatile("s_waitcnt vmcnt(4)" ::: "memory");
  else             asm volatile("s_waitcnt vmcnt(6)" ::: "memory");
}

// ---------------- merged prep kernel ----------------
// Packed layout per section: idx = ((tile*KC + kc)*2 + h)*256 + l31*8 + j
//   A-fragment element (l31, h, j) = Src[tile*32 + l31][kc*16 + h*8 + j]
// Block ranges: [0,768) Cbp | [768,1024) WXbp | [1024,3072) E0bp |
//               [3072,5120) E0Tbp | 5120 zero-tail

__global__ void prep_all(const float* __restrict__ W, const float* __restrict__ WX,
                         const float* __restrict__ E0,
                         short* __restrict__ Cbp, short* __restrict__ WXbp,
                         short* __restrict__ E0bp, short* __restrict__ E0Tbp,
                         float* __restrict__ out) {
  const int b = blockIdx.x;
  if (b < 768) {
    // Cbp: sections [C0, C1, -C1] (65536 shorts each), C = WX*W (256x256), KC=16
    const int idx = b * 256 + threadIdx.x;
    const int sec = idx >> 16, r = idx & 65535;
    const int j = r & 7, l31 = (r >> 3) & 31, h = (r >> 8) & 1, kc = (r >> 9) & 15, rt = r >> 13;
    const int i = rt * 32 + l31, col = kc * 16 + h * 8 + j;
    float c0 = 0.f, c1 = 0.f;
    for (int n = 0; n < 128; n++) {
      const float wx0 = WX[i * 128 + n], wx1 = WX[32768 + i * 128 + n];
      const float w0 = W[n * 256 + col], w1 = W[32768 + n * 256 + col];
      c0 += wx0 * w0 - wx1 * w1;
      c1 += wx0 * w1 + wx1 * w0;
    }
    Cbp[idx] = f2bf(sec == 0 ? c0 : (sec == 1 ? c1 : -c1));
  } else if (b < 1024) {
    // WXbp: sections [-WX0, -WX1] (32768 shorts each), rows k(256), cols n(128), KC=8
    const int idx = (b - 768) * 256 + threadIdx.x;
    const int sec = idx >> 15, r = idx & 32767;
    const int j = r & 7, l31 = (r >> 3) & 31, h = (r >> 8) & 1, kc = (r >> 9) & 7, rt = r >> 12;
    const int row = rt * 32 + l31, col = kc * 16 + h * 8 + j;
    WXbp[idx] = f2bf(-WX[sec * 32768 + row * 128 + col]);
  } else if (b < 3072) {
    // E0bp: sections [E0_re, -E0_im] (262144 shorts each), rows m(1024), cols k(256), KC=16
    const int idx = (b - 1024) * 256 + threadIdx.x;
    const int sec = idx >> 18, r = idx & 262143;
    const int j = r & 7, l31 = (r >> 3) & 31, h = (r >> 8) & 1, kc = (r >> 9) & 15, mt = r >> 13;
    const int m = mt * 32 + l31, k = kc * 16 + h * 8 + j;
    const float v = E0[sec * 262144 + m * 256 + k];
    E0bp[idx] = f2bf(sec ? -v : v);
  } else if (b < 5120) {
    // E0Tbp: sections [E0_re^T, -E0_im^T] (262144 shorts each), rows k(256), cols m(1024), KC=64
    const int idx = (b - 3072) * 256 + threadIdx.x;
    const int ch = idx >> 18, r = idx & 262143;
    const int j = r & 7, l31 = (r >> 3) & 31, h = (r >> 8) & 1, kc = (r >> 9) & 63, rt = r >> 15;
    const int krow = rt * 32 + l31, mcol = kc * 16 + h * 8 + j;
    const float v = E0[ch * 262144 + mcol * 256 + krow];
    E0Tbp[idx] = f2bf(ch ? -v : v);
  } else {
    if (threadIdx.x < 3) out[4194304 + threadIdx.x] = 0.f;
  }
}

// ---------------- main fused kernel ----------------
// grid 256 (batch tile of 32), block 512 (8 waves; wave w = row-tile).
// LDS: buf0 (32KB) = x bf16 [2][32][256] / aliased z chunk [32][512]
//      buf1 (32KB) = gx bf16 [2][32][256]
//      bufy (24KB) = y bf16 [y0|y1|-y1][32][128]  (persistent)
//      ring0..3 (4 x 16KB) = per-wave async staging slots (2KB/wave/slot)
// Total 152KB -> 1 block/CU.  Rows XOR-swizzled at 16B granules by (row&7).

#define SLOT_PTR(s) (((s) & 3) == 0 ? ring0 : ((s) & 3) == 1 ? ring1 : ((s) & 3) == 2 ? ring2 : ring3)

__global__ __attribute__((amdgpu_flat_work_group_size(512, 512), amdgpu_waves_per_eu(2, 2)))
void ista_main(
    const float* __restrict__ y,
    const float* __restrict__ etas,
    const float* __restrict__ gammas,
    const short* __restrict__ Cbp,
    const short* __restrict__ WXbp,
    const short* __restrict__ E0bp,
    const short* __restrict__ E0Tbp,
    float* __restrict__ out) {
  __shared__ short buf0[16384];
  __shared__ short buf1[16384];
  __shared__ short bufy[12288];
  __shared__ short ring0[8192];
  __shared__ short ring1[8192];
  __shared__ short ring2[8192];
  __shared__ short ring3[8192];

  const int tid = threadIdx.x;
  const int w = tid >> 6;          // wave 0..7 == row-tile
  const int lane = tid & 63;
  const int l31 = lane & 31;
  const int h = lane >> 5;         // half-wave
  const int sw = l31 & 7;          // swizzle key
  const int b0 = blockIdx.x * 32;
  const int lq = l31 * 8;          // packed-fragment lane offset (shorts)
  const int lane8 = lane * 8;      // per-lane global DMA offset (shorts)
  const int wslot = w * 1024;      // per-wave ring slot base (shorts)

  // ---- stage y -> bufy: [0]=y_re, [1]=y_im, [2]=-y_im
  {
    const int bt = tid >> 4, j = tid & 15;      // 16 threads per batch row
    const float* yb = y + (size_t)(b0 + bt) * 256;
    const int bsw = (bt & 7);
    #pragma unroll
    for (int rep = 0; rep < 2; rep++) {
      const int jj = j + rep * 16;
      const int ch = jj >> 4, n8 = (jj & 15) << 3;
      const float4 v0 = *(const float4*)(yb + ch * 128 + n8);
      const float4 v1 = *(const float4*)(yb + ch * 128 + n8 + 4);
      s8v pk;
      pk[0] = f2bf(v0.x); pk[1] = f2bf(v0.y); pk[2] = f2bf(v0.z); pk[3] = f2bf(v0.w);
      pk[4] = f2bf(v1.x); pk[5] = f2bf(v1.y); pk[6] = f2bf(v1.z); pk[7] = f2bf(v1.w);
      const int off = bt * 128 + (((n8 >> 3) ^ bsw) << 3);
      *(s8v*)(bufy + ch * 4096 + off) = pk;
      if (ch == 1) {
        s8v nk;
        #pragma unroll
        for (int e = 0; e < 8; e++) nk[e] = pk[e] ^ (short)0x8000;
        *(s8v*)(bufy + 8192 + off) = nk;
      }
    }
  }
  // ---- zero buf0 (x = 0): 512 threads x 32 shorts
  {
    s8v z = {0, 0, 0, 0, 0, 0, 0, 0};
    #pragma unroll
    for (int r = 0; r < 4; r++) *(s8v*)(buf0 + tid * 32 + r * 8) = z;
  }
  __syncthreads();

  float ls = 0.f, leq = 0.f, cntf = 0.f;
  f16v xm0, xm1;
  #pragma unroll
  for (int r = 0; r < 16; r++) { xm0[r] = 0.f; xm1[r] = 0.f; }

  #pragma unroll 1
  for (int it = 1; it <= 10; it++) {
    const float gam = gammas[it];
    const float eta = etas[it];

    // ======== Phase A: ac = C*x - d~ ; gx = x - gam*ac (both channels) ========
    f16v ac0, ac1;
    #pragma unroll
    for (int r = 0; r < 16; r++) { ac0[r] = 0.f; ac1[r] = 0.f; }
    #pragma unroll
    for (int kc = 0; kc < 8; kc++) {       // -d~ = (-WX) * y
      const int pa = ((w * 8 + kc) * 2 + h) * 256 + lq;
      const s8v a0 = *(const s8v*)(WXbp + pa);            // -WX0
      const s8v a1 = *(const s8v*)(WXbp + 32768 + pa);    // -WX1
      const int yo = l31 * 128 + ((((kc * 2 + h)) ^ sw) << 3);
      const s8v by0 = *(const s8v*)(bufy + yo);           // y0
      const s8v by1 = *(const s8v*)(bufy + 4096 + yo);    // y1
      const s8v by1n = *(const s8v*)(bufy + 8192 + yo);   // -y1
      ac0 = MFMA(a0, by0, ac0);
      ac0 = MFMA(a1, by1n, ac0);
      ac1 = MFMA(a0, by1, ac1);
      ac1 = MFMA(a1, by0, ac1);
    }
    #pragma unroll
    for (int kc = 0; kc < 16; kc++) {      // + C * x
      const int pa = ((w * 16 + kc) * 2 + h) * 256 + lq;
      const s8v a0 = *(const s8v*)(Cbp + pa);             // C0
      const s8v a1 = *(const s8v*)(Cbp + 65536 + pa);     // C1
      const s8v a1n = *(const s8v*)(Cbp + 131072 + pa);   // -C1
      const int xo = l31 * 256 + ((((kc * 2 + h)) ^ sw) << 3);
      const s8v bx0 = *(const s8v*)(buf0 + xo);
      const s8v bx1 = *(const s8v*)(buf0 + 8192 + xo);
      ac0 = MFMA(a0, bx0, ac0);
      ac0 = MFMA(a1n, bx1, ac0);
      ac1 = MFMA(a0, bx1, ac1);
      ac1 = MFMA(a1, bx0, ac1);
    }
    // gx = x - gam*ac  (x per-lane from LDS bf16); write gx bf16 -> buf1
    #pragma unroll
    for (int r1 = 0; r1 < 4; r1++) {
      const int k0 = w * 32 + 8 * r1 + 4 * h;
      const int idx = l31 * 256 + (((k0 >> 3) ^ sw) << 3) + (k0 & 7);
      const s4v xv0 = *(const s4v*)(buf0 + idx);
      const s4v xv1 = *(const s4v*)(buf0 + 8192 + idx);
      s4v p0, p1;
      #pragma unroll
      for (int r0 = 0; r0 < 4; r0++) {
        p0[r0] = f2bf(bf2f(xv0[r0]) - gam * ac0[r1 * 4 + r0]);
        p1[r0] = f2bf(bf2f(xv1[r0]) - gam * ac1[r1 * 4 + r0]);
      }
      *(s4v*)(buf1 + idx) = p0;
      *(s4v*)(buf1 + 8192 + idx) = p1;
    }
    __syncthreads();

    #pragma unroll
    for (int r = 0; r < 16; r++) { xm0[r] = 0.f; xm1[r] = 0.f; }

    #pragma unroll 1
    for (int c = 0; c < 2; c++) {
      // ---- Phase B: z = Re(E0 * gx); 2 m-tile passes per wave, async ring ----
      #pragma unroll 1
      for (int q = 0; q < 2; q++) {
        const int mt = c * 16 + q * 8 + w;
        f16v zq;
        #pragma unroll
        for (int r = 0; r < 16; r++) zq[r] = 0.f;

#define B_ISSUE(st) do { \
    const short* _b = E0bp + (mt * 16 + (st)) * 512; \
    short* _s = SLOT_PTR(st) + wslot; \
    glds16(_b + lane8, _s); \
    glds16(_b + 262144 + lane8, _s + 512); \
  } while (0)
#define B_CONSUME(st) do { \
    const short* _s = SLOT_PTR(st) + wslot; \
    const s8v aE0 = *(const s8v*)(_s + lane8); \
    const s8v aE1 = *(const s8v*)(_s + 512 + lane8); \
    const int xo = l31 * 256 + (((((st) * 2 + h)) ^ sw) << 3); \
    const s8v bg0 = *(const s8v*)(buf1 + xo); \
    const s8v bg1 = *(const s8v*)(buf1 + 8192 + xo); \
    zq = MFMA(aE0, bg0, zq); \
    zq = MFMA(aE1, bg1, zq); \
  } while (0)

        #pragma unroll
        for (int p = 0; p < 4; p++) B_ISSUE(p);
        #pragma unroll
        for (int kc = 0; kc < 16; kc++) {
          waitvm(2 * (15 - kc < 3 ? 15 - kc : 3));
          B_CONSUME(kc);
          if (kc + 4 < 16) B_ISSUE(kc + 4);
        }
#undef B_ISSUE
#undef B_CONSUME

        // shrink + losses + write z tile -> buf0 [32][512]
        const int mtl = q * 8 + w;
        #pragma unroll
        for (int r1 = 0; r1 < 4; r1++) {
          s4v ps;
          #pragma unroll
          for (int r0 = 0; r0 < 4; r0++) {
            const float v = zq[r1 * 4 + r0];
            const float av = fabsf(v) - eta;
            float s = 0.f;
            if (av > 0.f) {
              s = (v > 0.f) ? av : -av;
              ls += av;
              if (it == 10 && av > 1e-3f) cntf += 1.f;
            }
            ps[r0] = f2bf(s);
          }
          const int ml = mtl * 32 + 8 * r1 + 4 * h;
          *(s4v*)(buf0 + l31 * 512 + (((ml >> 3) ^ sw) << 3) + (ml & 7)) = ps;
        }
      }
      __syncthreads();

      // ---- Phase C: xm += [E0_re^T; -E0_im^T] * s, async ring over 32 kc ----
      {
#define C_ISSUE(st) do { \
    const short* _b = E0Tbp + (w * 64 + c * 32 + (st)) * 512; \
    short* _s = SLOT_PTR(st) + wslot; \
    glds16(_b + lane8, _s); \
    glds16(_b + 262144 + lane8, _s + 512); \
  } while (0)
#define C_CONSUME(st) do { \
    const short* _s = SLOT_PTR(st) + wslot; \
    const s8v aT0 = *(const s8v*)(_s + lane8); \
    const s8v aT1 = *(const s8v*)(_s + 512 + lane8); \
    const int zo = l31 * 512 + (((((st) * 2 + h)) ^ sw) << 3); \
    const s8v bz = *(const s8v*)(buf0 + zo); \
    xm0 = MFMA(aT0, bz, xm0); \
    xm1 = MFMA(aT1, bz, xm1); \
  } while (0)

        #pragma unroll
        for (int p = 0; p < 4; p++) C_ISSUE(p);
        #pragma unroll
        for (int kc = 0; kc < 32; kc++) {
          waitvm(2 * (31 - kc < 3 ? 31 - kc : 3));
          C_CONSUME(kc);
          if (kc + 4 < 32) C_ISSUE(kc + 4);
        }
#undef C_ISSUE
#undef C_CONSUME
      }
      __syncthreads();
    }

    // ======== Phase D: huber(gx, xm); x = xm (bf16) -> buf0 ========
    #pragma unroll
    for (int r1 = 0; r1 < 4; r1++) {
      const int k0 = w * 32 + 8 * r1 + 4 * h;
      const int idx = l31 * 256 + (((k0 >> 3) ^ sw) << 3) + (k0 & 7);
      const s4v gv0 = *(const s4v*)(buf1 + idx);
      const s4v gv1 = *(const s4v*)(buf1 + 8192 + idx);
      s4v p0, p1;
      #pragma unroll
      for (int r0 = 0; r0 < 4; r0++) {
        const float x0 = xm0[r1 * 4 + r0], x1 = xm1[r1 * 4 + r0];
        const float d0 = bf2f(gv0[r0]) - x0;
        const float d1 = bf2f(gv1[r0]) - x1;
        const float a0 = fabsf(d0), a1 = fabsf(d1);
        leq += (a0 < 1.f) ? 0.5f * d0 * d0 : (a0 - 0.5f);
        leq += (a1 < 1.f) ? 0.5f * d1 * d1 : (a1 - 0.5f);
        p0[r0] = f2bf(x0);
        p1[r0] = f2bf(x1);
      }
      *(s4v*)(buf0 + idx) = p0;
      *(s4v*)(buf0 + 8192 + idx) = p1;
    }
    __syncthreads();
  }

  // ---- write x_T (2, 8192, 256) fp32 from final xm (both channels)
  {
    const size_t ob = (size_t)(b0 + l31) * 256;
    #pragma unroll
    for (int r1 = 0; r1 < 4; r1++) {
      const int k0 = w * 32 + 8 * r1 + 4 * h;
      float4 v0, v1;
      v0.x = xm0[r1 * 4 + 0]; v0.y = xm0[r1 * 4 + 1]; v0.z = xm0[r1 * 4 + 2]; v0.w = xm0[r1 * 4 + 3];
      v1.x = xm1[r1 * 4 + 0]; v1.y = xm1[r1 * 4 + 1]; v1.z = xm1[r1 * 4 + 2]; v1.w = xm1[r1 * 4 + 3];
      *(float4*)(out + ob + k0) = v0;
      *(float4*)(out + 2097152 + ob + k0) = v1;
    }
  }
  // ---- scalar reductions
  #pragma unroll
  for (int off = 32; off > 0; off >>= 1) {
    ls += __shfl_down(ls, off);
    leq += __shfl_down(leq, off);
    cntf += __shfl_down(cntf, off);
  }
  if (lane == 0) {
    atomicAdd(out + 4194304, ls * (1.f / 8192.f));
    atomicAdd(out + 4194305, leq * (1.f / (2.f * 256.f * 8192.f * 10.f)));
    atomicAdd(out + 4194306, cntf * (1.f / 8192.f));
  }
}

extern "C" void kernel_launch(void* const* d_in, const int* in_sizes, int n_in,
                              void* d_out, int out_size, void* d_ws, size_t ws_size,
                              hipStream_t stream) {
  (void)in_sizes; (void)n_in; (void)out_size; (void)ws_size;
  const float* y = (const float*)d_in[0];
  const float* W = (const float*)d_in[1];
  const float* WX = (const float*)d_in[2];
  const float* E0 = (const float*)d_in[3];
  const float* etas = (const float*)d_in[4];
  const float* gammas = (const float*)d_in[5];
  float* out = (float*)d_out;

  short* Cbp = (short*)d_ws;           // 3 * 65536
  short* WXbp = Cbp + 196608;          // 2 * 32768
  short* E0bp = WXbp + 65536;          // 2 * 262144
  short* E0Tbp = E0bp + 524288;        // 2 * 262144  (total ~2.6 MB)

  prep_all<<<5121, 256, 0, stream>>>(W, WX, E0, Cbp, WXbp, E0bp, E0Tbp, out);
  ista_main<<<256, 512, 0, stream>>>(y, etas, gammas, Cbp, WXbp, E0bp, E0Tbp, out);
}

// Round 9
// 440.873 us; speedup vs baseline: 4.9938x; 1.4001x over previous
//
#include <hip/hip_runtime.h>
#include <stdint.h>

// ISTA_Net fused MFMA implementation for gfx950.  Round 9:
// R8 structure (async LDS-DMA rings, 580us) + fp8-e4m3 Phases B & C:
// - E0 / E0T weight streams stored fp8 (x16 pre-scale), gx / s stored fp8
//   with per-iteration dynamic scale S_i = 8^(i-1) (x grows ~9.3x/iter to
//   ~4.5e8 -- fixed-scale fp8 would saturate at 448).  Phase A stays bf16
//   (x state bf16 true-scale in LDS; bf16 range is unbounded here).
// - DMA granule: 16B/lane = 1KB/wave = one section's A-fragments for TWO
//   kc (K=32).  Ring: 3 slots x 2KB/wave (both sections) = 48KB LDS.
// - MFMA: v_mfma_f32_32x32x16_fp8_fp8 (same shape/rate as bf16; win = bytes:
//   weight stream 2.55 -> 1.55 MB/iter/CU, LDS b128 traffic nearly halved).
// Shapes: M=1024, N=128, K=256, T=10, BATCH=8192. LAMBD=1.
// Outputs: x_T(2,8192,256) ++ loss_sparse ++ loss_eq/T ++ out_sparse

typedef short s8v __attribute__((ext_vector_type(8)));   // 8 bf16 MFMA operand
typedef short s4v __attribute__((ext_vector_type(4)));
typedef float f16v __attribute__((ext_vector_type(16))); // 32x32 MFMA accumulator
typedef long long i64;

#define MFMA(a, b, c)  __builtin_amdgcn_mfma_f32_32x32x16_bf16((a), (b), (c), 0, 0, 0)
#define MFMA8(a, b, c) __builtin_amdgcn_mfma_f32_32x32x16_fp8_fp8((a), (b), (c), 0, 0, 0)

__device__ __forceinline__ short f2bf(float f) {
  uint32_t u = __builtin_bit_cast(uint32_t, f);
  u = (u + 0x7FFFu + ((u >> 16) & 1u)) >> 16;   // RNE
  return (short)u;
}
__device__ __forceinline__ float bf2f(short s) {
  uint32_t u = ((uint32_t)(uint16_t)s) << 16;
  return __builtin_bit_cast(float, u);
}
__device__ __forceinline__ unsigned char f2fp8(float v) {
  return (unsigned char)(__builtin_amdgcn_cvt_pk_fp8_f32(v, 0.f, 0, false) & 0xFF);
}
__device__ __forceinline__ int pk4fp8(float a, float b, float c, float d) {
  int r = __builtin_amdgcn_cvt_pk_fp8_f32(a, b, 0, false);
  r = __builtin_amdgcn_cvt_pk_fp8_f32(c, d, r, true);
  return r;
}

// async 16B/lane global->LDS DMA (per-lane gptr; wave-uniform LDS base,
// HW scatters lane i -> base + 16*i)
__device__ __forceinline__ void glds16(const void* g, void* l) {
  __builtin_amdgcn_global_load_lds(
      (const __attribute__((address_space(1))) void*)g,
      (__attribute__((address_space(3))) void*)l, 16, 0, 0);
}
__device__ __forceinline__ void waitvm(int n) {
  if (n <= 0)      asm volatile("s_waitcnt vmcnt(0)" ::: "memory");
  else if (n == 2) asm volatile("s_waitcnt vmcnt(2)" ::: "memory");
  else             asm volatile("s_waitcnt vmcnt(4)" ::: "memory");
}

// ---------------- merged prep kernel ----------------
// bf16 packed layout (Cbp/WXbp): idx = ((tile*KC + kc)*2 + h)*256 + l31*8 + j
// fp8 DMA-block layout (E0f8p/E0Tf8p): per (tile, dkc, sec) 1KB block;
//   byte u*8+jj, u = t*64 + h*32 + l31 -> element (k = (2dkc+t)*16 + h*8 + jj)
// Block ranges: [0,768) Cbp | [768,1024) WXbp | [1024,3072) E0f8p |
//               [3072,5120) E0Tf8p | 5120 zero-tail

__global__ void prep_all(const float* __restrict__ W, const float* __restrict__ WX,
                         const float* __restrict__ E0,
                         short* __restrict__ Cbp, short* __restrict__ WXbp,
                         unsigned char* __restrict__ E0f8p,
                         unsigned char* __restrict__ E0Tf8p,
                         float* __restrict__ out) {
  const int b = blockIdx.x;
  if (b < 768) {
    // Cbp: sections [C0, C1, -C1] (65536 shorts each), C = WX*W (256x256), KC=16
    const int idx = b * 256 + threadIdx.x;
    const int sec = idx >> 16, r = idx & 65535;
    const int j = r & 7, l31 = (r >> 3) & 31, h = (r >> 8) & 1, kc = (r >> 9) & 15, rt = r >> 13;
    const int i = rt * 32 + l31, col = kc * 16 + h * 8 + j;
    float c0 = 0.f, c1 = 0.f;
    for (int n = 0; n < 128; n++) {
      const float wx0 = WX[i * 128 + n], wx1 = WX[32768 + i * 128 + n];
      const float w0 = W[n * 256 + col], w1 = W[32768 + n * 256 + col];
      c0 += wx0 * w0 - wx1 * w1;
      c1 += wx0 * w1 + wx1 * w0;
    }
    Cbp[idx] = f2bf(sec == 0 ? c0 : (sec == 1 ? c1 : -c1));
  } else if (b < 1024) {
    // WXbp: sections [-WX0, -WX1] (32768 shorts each), rows k(256), cols n(128), KC=8
    const int idx = (b - 768) * 256 + threadIdx.x;
    const int sec = idx >> 15, r = idx & 32767;
    const int j = r & 7, l31 = (r >> 3) & 31, h = (r >> 8) & 1, kc = (r >> 9) & 7, rt = r >> 12;
    const int row = rt * 32 + l31, col = kc * 16 + h * 8 + j;
    WXbp[idx] = f2bf(-WX[sec * 32768 + row * 128 + col]);
  } else if (b < 3072) {
    // E0f8p: sections [16*E0_re, -16*E0_im], rows m(1024), cols k(256); 8 dkc/m-tile
    const int idx = (b - 1024) * 256 + threadIdx.x;   // [0, 524288)
    const int sec = idx >> 18, r = idx & 262143;
    const int blk = r >> 10, within = r & 1023;
    const int mt = blk >> 3, dkc = blk & 7;
    const int u = within >> 3, jj = within & 7;
    const int t = u >> 6, h = (u >> 5) & 1, l31 = u & 31;
    const int m = mt * 32 + l31, k = (dkc * 2 + t) * 16 + h * 8 + jj;
    const float v = E0[sec * 262144 + m * 256 + k] * (sec ? -16.f : 16.f);
    E0f8p[idx] = f2fp8(v);
  } else if (b < 5120) {
    // E0Tf8p: sections [16*E0_re^T, -16*E0_im^T], rows k(256), cols m(1024);
    // blocks (rt, c, dkc16)
    const int idx = (b - 3072) * 256 + threadIdx.x;   // [0, 524288)
    const int sec = idx >> 18, r = idx & 262143;
    const int blk = r >> 10, within = r & 1023;
    const int rt = blk >> 5, rem = blk & 31;
    const int c = rem >> 4, dkc = rem & 15;
    const int u = within >> 3, jj = within & 7;
    const int t = u >> 6, h = (u >> 5) & 1, l31 = u & 31;
    const int krow = rt * 32 + l31;
    const int mcol = c * 512 + (dkc * 2 + t) * 16 + h * 8 + jj;
    const float v = E0[sec * 262144 + mcol * 256 + krow] * (sec ? -16.f : 16.f);
    E0Tf8p[idx] = f2fp8(v);
  } else {
    if (threadIdx.x < 3) out[4194304 + threadIdx.x] = 0.f;
  }
}

// ---------------- main fused kernel ----------------
// grid 256 (batch tile of 32), block 512 (8 waves; wave w = row-tile).
// LDS: buf0 (32KB) = x bf16 [2][32][256]; first 16KB aliased as zf8 [32][512]
//      buf1 (32KB) = gx bf16 (true scale, for Phase D huber)
//      bufy (24KB) = y bf16 [y0|y1|-y1][32][128]
//      gxf8 (16KB) = gx/S fp8 [2][32][256]   (Phase B B-operand)
//      ring0..2 (3 x 16KB) = per-wave DMA slots (2KB/wave: sec0 1KB | sec1 1KB)
// Total 152KB -> 1 block/CU.

#define RING(s) (((s) % 3) == 0 ? ring0 : ((s) % 3) == 1 ? ring1 : ring2)

__global__ __attribute__((amdgpu_flat_work_group_size(512, 512), amdgpu_waves_per_eu(2, 2)))
void ista_main(
    const float* __restrict__ y,
    const float* __restrict__ etas,
    const float* __restrict__ gammas,
    const short* __restrict__ Cbp,
    const short* __restrict__ WXbp,
    const unsigned char* __restrict__ E0f8p,
    const unsigned char* __restrict__ E0Tf8p,
    float* __restrict__ out) {
  __shared__ short buf0[16384];
  __shared__ short buf1[16384];
  __shared__ short bufy[12288];
  __shared__ unsigned char gxf8[16384];
  __shared__ unsigned char ring0[16384];
  __shared__ unsigned char ring1[16384];
  __shared__ unsigned char ring2[16384];
  unsigned char* zf8 = (unsigned char*)buf0;   // [32][512] fp8, aliases x-ch0

  const int tid = threadIdx.x;
  const int w = tid >> 6;          // wave 0..7 == row-tile
  const int lane = tid & 63;
  const int l31 = lane & 31;
  const int h = lane >> 5;         // half-wave
  const int sw = l31 & 7;          // swizzle key
  const int b0 = blockIdx.x * 32;
  const int lq = l31 * 8;          // bf16 packed-fragment lane offset (shorts)
  const int lane16 = lane * 16;    // per-lane global DMA offset (bytes)
  const int wslot = w * 2048;      // per-wave ring slot base (bytes)

  // ---- stage y -> bufy: [0]=y_re, [1]=y_im, [2]=-y_im
  {
    const int bt = tid >> 4, j = tid & 15;
    const float* yb = y + (size_t)(b0 + bt) * 256;
    const int bsw = (bt & 7);
    #pragma unroll
    for (int rep = 0; rep < 2; rep++) {
      const int jj = j + rep * 16;
      const int ch = jj >> 4, n8 = (jj & 15) << 3;
      const float4 v0 = *(const float4*)(yb + ch * 128 + n8);
      const float4 v1 = *(const float4*)(yb + ch * 128 + n8 + 4);
      s8v pk;
      pk[0] = f2bf(v0.x); pk[1] = f2bf(v0.y); pk[2] = f2bf(v0.z); pk[3] = f2bf(v0.w);
      pk[4] = f2bf(v1.x); pk[5] = f2bf(v1.y); pk[6] = f2bf(v1.z); pk[7] = f2bf(v1.w);
      const int off = bt * 128 + (((n8 >> 3) ^ bsw) << 3);
      *(s8v*)(bufy + ch * 4096 + off) = pk;
      if (ch == 1) {
        s8v nk;
        #pragma unroll
        for (int e = 0; e < 8; e++) nk[e] = pk[e] ^ (short)0x8000;
        *(s8v*)(bufy + 8192 + off) = nk;
      }
    }
  }
  // ---- zero buf0 (x = 0)
  {
    s8v z = {0, 0, 0, 0, 0, 0, 0, 0};
    #pragma unroll
    for (int r = 0; r < 4; r++) *(s8v*)(buf0 + tid * 32 + r * 8) = z;
  }
  __syncthreads();

  float ls = 0.f, leq = 0.f, cntf = 0.f;
  float S = 1.f;                   // dynamic scale: gx/S, s/S stored fp8
  float s16_last = 0.0625f;
  f16v xm0, xm1;
  #pragma unroll
  for (int r = 0; r < 16; r++) { xm0[r] = 0.f; xm1[r] = 0.f; }

  #pragma unroll 1
  for (int it = 1; it <= 10; it++) {
    const float gam = gammas[it];
    const float eta = etas[it];
    const float invS = 1.f / S;
    const float s16 = S * 0.0625f;   // accumulator -> true scale (weights x16)
    s16_last = s16;

    // ======== Phase A (bf16): ac = C*x - d~ ; gx = x - gam*ac ========
    f16v ac0, ac1;
    #pragma unroll
    for (int r = 0; r < 16; r++) { ac0[r] = 0.f; ac1[r] = 0.f; }
    #pragma unroll
    for (int kc = 0; kc < 8; kc++) {       // -d~ = (-WX) * y
      const int pa = ((w * 8 + kc) * 2 + h) * 256 + lq;
      const s8v a0 = *(const s8v*)(WXbp + pa);
      const s8v a1 = *(const s8v*)(WXbp + 32768 + pa);
      const int yo = l31 * 128 + ((((kc * 2 + h)) ^ sw) << 3);
      const s8v by0 = *(const s8v*)(bufy + yo);
      const s8v by1 = *(const s8v*)(bufy + 4096 + yo);
      const s8v by1n = *(const s8v*)(bufy + 8192 + yo);
      ac0 = MFMA(a0, by0, ac0);
      ac0 = MFMA(a1, by1n, ac0);
      ac1 = MFMA(a0, by1, ac1);
      ac1 = MFMA(a1, by0, ac1);
    }
    if (it > 1) {
      #pragma unroll
      for (int kc = 0; kc < 16; kc++) {    // + C * x   (x = 0 at it=1)
        const int pa = ((w * 16 + kc) * 2 + h) * 256 + lq;
        const s8v a0 = *(const s8v*)(Cbp + pa);
        const s8v a1 = *(const s8v*)(Cbp + 65536 + pa);
        const s8v a1n = *(const s8v*)(Cbp + 131072 + pa);
        const int xo = l31 * 256 + ((((kc * 2 + h)) ^ sw) << 3);
        const s8v bx0 = *(const s8v*)(buf0 + xo);
        const s8v bx1 = *(const s8v*)(buf0 + 8192 + xo);
        ac0 = MFMA(a0, bx0, ac0);
        ac0 = MFMA(a1n, bx1, ac0);
        ac1 = MFMA(a0, bx1, ac1);
        ac1 = MFMA(a1, bx0, ac1);
      }
    }
    // gx = x - gam*ac; write gx bf16 (true) -> buf1, gx*invS fp8 -> gxf8
    #pragma unroll
    for (int r1 = 0; r1 < 4; r1++) {
      const int k0 = w * 32 + 8 * r1 + 4 * h;
      const int idx = l31 * 256 + (((k0 >> 3) ^ sw) << 3) + (k0 & 7);
      const s4v xv0 = *(const s4v*)(buf0 + idx);
      const s4v xv1 = *(const s4v*)(buf0 + 8192 + idx);
      float g0[4], g1[4];
      s4v p0, p1;
      #pragma unroll
      for (int r0 = 0; r0 < 4; r0++) {
        g0[r0] = bf2f(xv0[r0]) - gam * ac0[r1 * 4 + r0];
        g1[r0] = bf2f(xv1[r0]) - gam * ac1[r1 * 4 + r0];
        p0[r0] = f2bf(g0[r0]);
        p1[r0] = f2bf(g1[r0]);
      }
      *(s4v*)(buf1 + idx) = p0;
      *(s4v*)(buf1 + 8192 + idx) = p1;
      const int ga = l31 * 256 + (((k0 >> 4) ^ sw) << 4) + (k0 & 15);
      *(int*)(gxf8 + ga) = pk4fp8(g0[0] * invS, g0[1] * invS, g0[2] * invS, g0[3] * invS);
      *(int*)(gxf8 + 8192 + ga) = pk4fp8(g1[0] * invS, g1[1] * invS, g1[2] * invS, g1[3] * invS);
    }
    __syncthreads();

    #pragma unroll
    for (int r = 0; r < 16; r++) { xm0[r] = 0.f; xm1[r] = 0.f; }

    #pragma unroll 1
    for (int c = 0; c < 2; c++) {
      // ---- Phase B (fp8): z = Re(E0 * gx); 2 m-tile passes, 3-slot DMA ring ----
      #pragma unroll 1
      for (int q = 0; q < 2; q++) {
        const int mt = c * 16 + q * 8 + w;
        const unsigned char* gb = E0f8p + (size_t)(mt * 8) * 1024 + lane16;
        f16v zq;
        #pragma unroll
        for (int r = 0; r < 16; r++) zq[r] = 0.f;

#define B_ISSUE(d) do { \
    unsigned char* _s = RING(d) + wslot; \
    glds16(gb + (d) * 1024, _s); \
    glds16(gb + 262144 + (d) * 1024, _s + 1024); \
  } while (0)

        B_ISSUE(0); B_ISSUE(1); B_ISSUE(2);
        #pragma unroll
        for (int dkc = 0; dkc < 8; dkc++) {
          waitvm(2 * (7 - dkc < 2 ? 7 - dkc : 2));
          const unsigned char* Sl = RING(dkc) + wslot;
          #pragma unroll
          for (int t = 0; t < 2; t++) {
            const i64 are = *(const i64*)(Sl + t * 512 + h * 256 + l31 * 8);
            const i64 aim = *(const i64*)(Sl + 1024 + t * 512 + h * 256 + l31 * 8);
            const int kc = dkc * 2 + t;
            const int go = l31 * 256 + ((kc ^ sw) << 4) + h * 8;
            const i64 bg0 = *(const i64*)(gxf8 + go);
            const i64 bg1 = *(const i64*)(gxf8 + 8192 + go);
            zq = MFMA8(are, bg0, zq);
            zq = MFMA8(aim, bg1, zq);
          }
          if (dkc + 3 < 8) B_ISSUE(dkc + 3);
        }
#undef B_ISSUE

        // shrink + losses; write s*invS fp8 -> zf8 [32][512]
        const int mtl = q * 8 + w;
        #pragma unroll
        for (int r1 = 0; r1 < 4; r1++) {
          float sv[4];
          #pragma unroll
          for (int r0 = 0; r0 < 4; r0++) {
            const float v = zq[r1 * 4 + r0] * s16;   // true z
            const float av = fabsf(v) - eta;
            float s = 0.f;
            if (av > 0.f) {
              s = (v > 0.f) ? av : -av;
              ls += av;
              if (it == 10 && av > 1e-3f) cntf += 1.f;
            }
            sv[r0] = s * invS;
          }
          const int ml = mtl * 32 + 8 * r1 + 4 * h;
          const int za = l31 * 512 + (((ml >> 4) ^ sw) << 4) + (ml & 15);
          *(int*)(zf8 + za) = pk4fp8(sv[0], sv[1], sv[2], sv[3]);
        }
      }
      __syncthreads();

      // ---- Phase C (fp8): xm += [E0reT; -E0imT] * s, 3-slot DMA ring ----
      {
        const unsigned char* tb = E0Tf8p + (size_t)((w * 2 + c) * 16) * 1024 + lane16;
#define C_ISSUE(d) do { \
    unsigned char* _s = RING(d) + wslot; \
    glds16(tb + (d) * 1024, _s); \
    glds16(tb + 262144 + (d) * 1024, _s + 1024); \
  } while (0)

        C_ISSUE(0); C_ISSUE(1); C_ISSUE(2);
        #pragma unroll
        for (int dkc = 0; dkc < 16; dkc++) {
          waitvm(2 * (15 - dkc < 2 ? 15 - dkc : 2));
          const unsigned char* Sl = RING(dkc) + wslot;
          #pragma unroll
          for (int t = 0; t < 2; t++) {
            const i64 a0 = *(const i64*)(Sl + t * 512 + h * 256 + l31 * 8);
            const i64 a1 = *(const i64*)(Sl + 1024 + t * 512 + h * 256 + l31 * 8);
            const int kc = dkc * 2 + t;
            const i64 bz = *(const i64*)(zf8 + l31 * 512 + ((kc ^ sw) << 4) + h * 8);
            xm0 = MFMA8(a0, bz, xm0);
            xm1 = MFMA8(a1, bz, xm1);
          }
          if (dkc + 3 < 16) C_ISSUE(dkc + 3);
        }
#undef C_ISSUE
      }
      __syncthreads();
    }

    // ======== Phase D: huber(gx, xm*s16); x = xm*s16 (bf16) -> buf0 ========
    #pragma unroll
    for (int r1 = 0; r1 < 4; r1++) {
      const int k0 = w * 32 + 8 * r1 + 4 * h;
      const int idx = l31 * 256 + (((k0 >> 3) ^ sw) << 3) + (k0 & 7);
      const s4v gv0 = *(const s4v*)(buf1 + idx);
      const s4v gv1 = *(const s4v*)(buf1 + 8192 + idx);
      s4v p0, p1;
      #pragma unroll
      for (int r0 = 0; r0 < 4; r0++) {
        const float x0 = xm0[r1 * 4 + r0] * s16, x1 = xm1[r1 * 4 + r0] * s16;
        const float d0 = bf2f(gv0[r0]) - x0;
        const float d1 = bf2f(gv1[r0]) - x1;
        const float a0 = fabsf(d0), a1 = fabsf(d1);
        leq += (a0 < 1.f) ? 0.5f * d0 * d0 : (a0 - 0.5f);
        leq += (a1 < 1.f) ? 0.5f * d1 * d1 : (a1 - 0.5f);
        p0[r0] = f2bf(x0);
        p1[r0] = f2bf(x1);
      }
      *(s4v*)(buf0 + idx) = p0;
      *(s4v*)(buf0 + 8192 + idx) = p1;
    }
    __syncthreads();
    S *= 8.f;   // x grows ~9.3x/iter; keep fp8-stored gx/s near O(1)
  }

  // ---- write x_T (2, 8192, 256) fp32 from final xm (true scale)
  {
    const size_t ob = (size_t)(b0 + l31) * 256;
    #pragma unroll
    for (int r1 = 0; r1 < 4; r1++) {
      const int k0 = w * 32 + 8 * r1 + 4 * h;
      float4 v0, v1;
      v0.x = xm0[r1 * 4 + 0] * s16_last; v0.y = xm0[r1 * 4 + 1] * s16_last;
      v0.z = xm0[r1 * 4 + 2] * s16_last; v0.w = xm0[r1 * 4 + 3] * s16_last;
      v1.x = xm1[r1 * 4 + 0] * s16_last; v1.y = xm1[r1 * 4 + 1] * s16_last;
      v1.z = xm1[r1 * 4 + 2] * s16_last; v1.w = xm1[r1 * 4 + 3] * s16_last;
      *(float4*)(out + ob + k0) = v0;
      *(float4*)(out + 2097152 + ob + k0) = v1;
    }
  }
  // ---- scalar reductions
  #pragma unroll
  for (int off = 32; off > 0; off >>= 1) {
    ls += __shfl_down(ls, off);
    leq += __shfl_down(leq, off);
    cntf += __shfl_down(cntf, off);
  }
  if (lane == 0) {
    atomicAdd(out + 4194304, ls * (1.f / 8192.f));
    atomicAdd(out + 4194305, leq * (1.f / (2.f * 256.f * 8192.f * 10.f)));
    atomicAdd(out + 4194306, cntf * (1.f / 8192.f));
  }
}

extern "C" void kernel_launch(void* const* d_in, const int* in_sizes, int n_in,
                              void* d_out, int out_size, void* d_ws, size_t ws_size,
                              hipStream_t stream) {
  (void)in_sizes; (void)n_in; (void)out_size; (void)ws_size;
  const float* y = (const float*)d_in[0];
  const float* W = (const float*)d_in[1];
  const float* WX = (const float*)d_in[2];
  const float* E0 = (const float*)d_in[3];
  const float* etas = (const float*)d_in[4];
  const float* gammas = (const float*)d_in[5];
  float* out = (float*)d_out;

  short* Cbp = (short*)d_ws;                       // 3 * 65536 shorts
  short* WXbp = Cbp + 196608;                      // 2 * 32768 shorts
  unsigned char* E0f8p = (unsigned char*)(WXbp + 65536);   // 524288 B
  unsigned char* E0Tf8p = E0f8p + 524288;                  // 524288 B (~1.6 MB total)

  prep_all<<<5121, 256, 0, stream>>>(W, WX, E0, Cbp, WXbp, E0f8p, E0Tf8p, out);
  ista_main<<<256, 512, 0, stream>>>(y, etas, gammas, Cbp, WXbp, E0f8p, E0Tf8p, out);
}